// Round 7
// baseline (452.070 us; speedup 1.0000x reference)
//
#include <hip/hip_runtime.h>
#include <hip/hip_cooperative_groups.h>

namespace cg = cooperative_groups;

#define N_NODES 100000
#define N_EDGES 1600000
#define IN_F    256
#define OUT_F   128

#define BROWS2   256                  // rows per bucket
#define NB2      391                  // ceil(N_NODES / 256)
#define CAPB     4800                 // slots/bucket (mean 4096, sigma 64 -> +11 sigma)
#define PART_EPB 4096                 // edges per partition chunk
#define NPARTC   391                  // ceil(N_EDGES / PART_EPB)
#define KE       (PART_EPB / 256)     // 16 edges/thread in partition
#define KB       ((CAPB + 255) / 256) // 19 edges/thread in bucket build
#define NGEMM    1563                 // ceil(N_NODES / 64) gemm tiles

typedef __attribute__((ext_vector_type(8))) short   s16x8;   // 8 x bf16 (MFMA A/B frag)
typedef __attribute__((ext_vector_type(4))) float   f32x4;   // MFMA C/D frag
typedef __attribute__((ext_vector_type(8))) unsigned short u16x8;

__device__ __forceinline__ unsigned short f2bf(float f) {   // fp32 -> bf16 RNE
    unsigned u = __float_as_uint(f);
    u += 0x7FFFu + ((u >> 16) & 1u);
    return (unsigned short)(u >> 16);
}
__device__ __forceinline__ float bf2f(unsigned short h) {
    return __uint_as_float((unsigned)h << 16);
}

struct SmG {                            // gemm phase (32768 B exactly)
    unsigned short As[64][40];
    unsigned short Bs[128][40];
    unsigned short Ct[64][136];
};
struct SmP { int cnt[NB2]; int basep[NB2]; };          // partition phase
struct SmB { int cnt[BROWS2]; int excl[BROWS2]; int wsum[4]; };  // bucket phase

// ===========================================================================
// MEGA (cooperative): P0 wt/zero -> P1 partition -> P2 gemm -> P3 bucket.
// Phase bodies are byte-identical to the r5-verified standalone kernels;
// grid.sync() replaces 3 launch boundaries (measured ~20-25us each, r6
// accounting). No block-role overlap (r6 showed fusion-by-role = no overlap).
// ===========================================================================
__global__ __launch_bounds__(256) void mega(const float* __restrict__ X,
                                            const int* __restrict__ arow,
                                            const int* __restrict__ acol,
                                            const float* __restrict__ aval,
                                            const float* __restrict__ W,
                                            unsigned short* __restrict__ support,
                                            unsigned short* __restrict__ Wt,
                                            int* __restrict__ cursorA,
                                            int2* __restrict__ epackA,
                                            int2* __restrict__ rowmeta,
                                            int2* __restrict__ epackB) {
    __shared__ union { SmG g; SmP p; SmB b; } sm;
    cg::grid_group grid = cg::this_grid();
    const int t   = threadIdx.x;
    const int bid = blockIdx.x;
    const int nb  = gridDim.x;

    // ---------------- P0: Wt[n][k] = bf16(W[k][n]); zero cursors ----------
    for (int n = bid; n < OUT_F; n += nb)
        Wt[n * IN_F + t] = f2bf(W[(size_t)t * OUT_F + n]);
    if (bid == 0)
        for (int k = t; k < NB2; k += 256) cursorA[k] = 0;
    grid.sync();

    // ---------------- P1: partition edges into 391 coarse buckets ---------
    for (int c = bid; c < NPARTC; c += nb) {
        for (int k = t; k < NB2; k += 256) sm.p.cnt[k] = 0;
        __syncthreads();

        const int base = c * PART_EPB;
        int pk_[KE], vv_[KE], b_[KE], rk_[KE];
#pragma unroll
        for (int k = 0; k < KE; ++k) {
            const int i = base + t + k * 256;
            b_[k] = -1;
            if (i < N_EDGES) {
                const int r = arow[i];
                b_[k]  = r >> 8;
                pk_[k] = ((r & (BROWS2 - 1)) << 17) | acol[i];
                vv_[k] = __float_as_int(aval[i]);
                rk_[k] = atomicAdd(&sm.p.cnt[b_[k]], 1);      // LDS, 1/edge
            }
        }
        __syncthreads();
        for (int k = t; k < NB2; k += 256) {
            const int cc = sm.p.cnt[k];
            if (cc > 0) sm.p.basep[k] = atomicAdd(&cursorA[k], cc);
        }
        __syncthreads();
#pragma unroll
        for (int k = 0; k < KE; ++k) {
            if (b_[k] >= 0) {
                const int pos = sm.p.basep[b_[k]] + rk_[k];
                if (pos < CAPB)      // 11-sigma guard
                    epackA[(size_t)b_[k] * CAPB + pos] = make_int2(pk_[k], vv_[k]);
            }
        }
        __syncthreads();
    }
    grid.sync();

    // ---------------- P2: support = bf16(X @ W), 64x128 MFMA tiles --------
    for (int tile = bid; tile < NGEMM; tile += nb) {
        const int wid  = t >> 6;
        const int lane = t & 63;
        const int tm   = lane & 15;
        const int quad = lane >> 4;
        const int row0 = tile * 64;

        f32x4 acc[8];
#pragma unroll
        for (int c = 0; c < 8; ++c) acc[c] = (f32x4){0.f, 0.f, 0.f, 0.f};

        for (int kb = 0; kb < IN_F; kb += 32) {
            {
                const int m  = t >> 2;
                const int k0 = (t & 3) * 8;
                const int gr = row0 + m;
                float4 x0 = make_float4(0.f, 0.f, 0.f, 0.f), x1 = x0;
                if (gr < N_NODES) {
                    const float* xp = &X[(size_t)gr * IN_F + kb + k0];
                    x0 = *(const float4*)xp;
                    x1 = *(const float4*)(xp + 4);
                }
                ushort4 a0, a1;
                a0.x = f2bf(x0.x); a0.y = f2bf(x0.y); a0.z = f2bf(x0.z); a0.w = f2bf(x0.w);
                a1.x = f2bf(x1.x); a1.y = f2bf(x1.y); a1.z = f2bf(x1.z); a1.w = f2bf(x1.w);
                *(ushort4*)&sm.g.As[m][k0]     = a0;
                *(ushort4*)&sm.g.As[m][k0 + 4] = a1;
            }
            {
                const int n  = t >> 1;
                const int k0 = (t & 1) * 16;
                const unsigned short* wp = &Wt[(size_t)n * IN_F + kb + k0];
                *(u16x8*)&sm.g.Bs[n][k0]     = *(const u16x8*)wp;
                *(u16x8*)&sm.g.Bs[n][k0 + 8] = *(const u16x8*)(wp + 8);
            }
            __syncthreads();

            const s16x8 a = *(const s16x8*)&sm.g.As[wid * 16 + tm][quad * 8];
#pragma unroll
            for (int c = 0; c < 8; ++c) {
                const s16x8 b = *(const s16x8*)&sm.g.Bs[c * 16 + tm][quad * 8];
                acc[c] = __builtin_amdgcn_mfma_f32_16x16x32_bf16(a, b, acc[c], 0, 0, 0);
            }
            __syncthreads();
        }

#pragma unroll
        for (int c = 0; c < 8; ++c) {
            const int col = c * 16 + tm;
#pragma unroll
            for (int reg = 0; reg < 4; ++reg) {
                const int m = wid * 16 + quad * 4 + reg;
                sm.g.Ct[m][col] = f2bf(acc[c][reg]);
            }
        }
        __syncthreads();
        {
            const int m   = t >> 2;
            const int seg = (t & 3) * 32;
            const int gr  = row0 + m;
            if (gr < N_NODES) {
                unsigned short* op = &support[(size_t)gr * OUT_F + seg];
#pragma unroll
                for (int i = 0; i < 4; ++i)
                    *(u16x8*)(op + i * 8) = *(const u16x8*)&sm.g.Ct[m][seg + i * 8];
            }
        }
        __syncthreads();
    }
    grid.sync();

    // ---------------- P3: per-bucket exact CSR build ----------------------
    for (int b = bid; b < NB2; b += nb) {
        sm.b.cnt[t] = 0;
        __syncthreads();

        const size_t sa = (size_t)b * CAPB;
        const int n = min(cursorA[b], CAPB);

        int pk_[KB], vv_[KB], rk_[KB];
#pragma unroll
        for (int k = 0; k < KB; ++k) {
            const int i = t + k * 256;
            rk_[k] = -1;
            if (i < n) {
                const int2 e = epackA[sa + i];
                pk_[k] = e.x;
                vv_[k] = e.y;
                rk_[k] = atomicAdd(&sm.b.cnt[e.x >> 17], 1);   // LDS, 1/edge
            }
        }
        __syncthreads();

        {
            const int lane = t & 63;
            const int my   = sm.b.cnt[t];
            int x = my;
#pragma unroll
            for (int off = 1; off < 64; off <<= 1) {
                const int y = __shfl_up(x, off, 64);
                if (lane >= off) x += y;
            }
            if (lane == 63) sm.b.wsum[t >> 6] = x;
            __syncthreads();
            int pre = x - my;
            const int w = t >> 6;
            for (int kk = 0; kk < w; ++kk) pre += sm.b.wsum[kk];
            sm.b.excl[t] = pre;
            const int r = b * BROWS2 + t;
            if (r < N_NODES) rowmeta[r] = make_int2((int)sa + pre, my);
        }
        __syncthreads();

#pragma unroll
        for (int k = 0; k < KB; ++k) {
            if (rk_[k] >= 0) {
                const int rl  = pk_[k] >> 17;
                const int pos = sm.b.excl[rl] + rk_[k];
                epackB[sa + pos] = make_int2(pk_[k] & 0x1FFFF, vv_[k]);
            }
        }
        __syncthreads();
    }
}

// ===========================================================================
// Fallback standalone kernels (byte-identical to r5-verified versions) —
// used only if the cooperative launch is rejected by the runtime.
// ===========================================================================
__global__ __launch_bounds__(256) void wt_build(const float* __restrict__ W,
                                                unsigned short* __restrict__ Wt,
                                                int* __restrict__ cursorA) {
    const int n = blockIdx.x;
    const int k = threadIdx.x;
    Wt[n * IN_F + k] = f2bf(W[(size_t)k * OUT_F + n]);
    const int idx = blockIdx.x * 256 + threadIdx.x;
    if (idx < NB2) cursorA[idx] = 0;
}

__global__ __launch_bounds__(256) void gemm_mfma(const float* __restrict__ X,
                                                 const unsigned short* __restrict__ Wt,
                                                 unsigned short* __restrict__ support) {
    __shared__ unsigned short As[64][40];
    __shared__ unsigned short Bs[128][40];
    __shared__ unsigned short Ct[64][136];

    const int t    = threadIdx.x;
    const int wid  = t >> 6;
    const int lane = t & 63;
    const int tm   = lane & 15;
    const int quad = lane >> 4;
    const int row0 = blockIdx.x * 64;

    f32x4 acc[8];
#pragma unroll
    for (int c = 0; c < 8; ++c) acc[c] = (f32x4){0.f, 0.f, 0.f, 0.f};

    for (int kb = 0; kb < IN_F; kb += 32) {
        {
            const int m  = t >> 2;
            const int k0 = (t & 3) * 8;
            const int gr = row0 + m;
            float4 x0 = make_float4(0.f, 0.f, 0.f, 0.f), x1 = x0;
            if (gr < N_NODES) {
                const float* xp = &X[(size_t)gr * IN_F + kb + k0];
                x0 = *(const float4*)xp;
                x1 = *(const float4*)(xp + 4);
            }
            ushort4 a0, a1;
            a0.x = f2bf(x0.x); a0.y = f2bf(x0.y); a0.z = f2bf(x0.z); a0.w = f2bf(x0.w);
            a1.x = f2bf(x1.x); a1.y = f2bf(x1.y); a1.z = f2bf(x1.z); a1.w = f2bf(x1.w);
            *(ushort4*)&As[m][k0]     = a0;
            *(ushort4*)&As[m][k0 + 4] = a1;
        }
        {
            const int n  = t >> 1;
            const int k0 = (t & 1) * 16;
            const unsigned short* wp = &Wt[(size_t)n * IN_F + kb + k0];
            *(u16x8*)&Bs[n][k0]     = *(const u16x8*)wp;
            *(u16x8*)&Bs[n][k0 + 8] = *(const u16x8*)(wp + 8);
        }
        __syncthreads();

        const s16x8 a = *(const s16x8*)&As[wid * 16 + tm][quad * 8];
#pragma unroll
        for (int c = 0; c < 8; ++c) {
            const s16x8 b = *(const s16x8*)&Bs[c * 16 + tm][quad * 8];
            acc[c] = __builtin_amdgcn_mfma_f32_16x16x32_bf16(a, b, acc[c], 0, 0, 0);
        }
        __syncthreads();
    }

#pragma unroll
    for (int c = 0; c < 8; ++c) {
        const int col = c * 16 + tm;
#pragma unroll
        for (int reg = 0; reg < 4; ++reg) {
            const int m = wid * 16 + quad * 4 + reg;
            Ct[m][col] = f2bf(acc[c][reg]);
        }
    }
    __syncthreads();
    {
        const int m   = t >> 2;
        const int seg = (t & 3) * 32;
        const int gr  = row0 + m;
        if (gr < N_NODES) {
            unsigned short* op = &support[(size_t)gr * OUT_F + seg];
#pragma unroll
            for (int i = 0; i < 4; ++i)
                *(u16x8*)(op + i * 8) = *(const u16x8*)&Ct[m][seg + i * 8];
        }
    }
}

__global__ __launch_bounds__(256) void partition_edges(const int* __restrict__ arow,
                                                       const int* __restrict__ acol,
                                                       const float* __restrict__ aval,
                                                       int* __restrict__ cursorA,
                                                       int2* __restrict__ epackA) {
    __shared__ int cnt[NB2];
    __shared__ int basep[NB2];
    const int t = threadIdx.x;
    for (int k = t; k < NB2; k += 256) cnt[k] = 0;
    __syncthreads();

    const int base = blockIdx.x * PART_EPB;
    int pk_[KE], vv_[KE], b_[KE], rk_[KE];
#pragma unroll
    for (int k = 0; k < KE; ++k) {
        const int i = base + t + k * 256;
        b_[k] = -1;
        if (i < N_EDGES) {
            const int r = arow[i];
            b_[k]  = r >> 8;
            pk_[k] = ((r & (BROWS2 - 1)) << 17) | acol[i];
            vv_[k] = __float_as_int(aval[i]);
            rk_[k] = atomicAdd(&cnt[b_[k]], 1);
        }
    }
    __syncthreads();
    for (int k = t; k < NB2; k += 256) {
        const int c = cnt[k];
        if (c > 0) basep[k] = atomicAdd(&cursorA[k], c);
    }
    __syncthreads();
#pragma unroll
    for (int k = 0; k < KE; ++k) {
        if (b_[k] >= 0) {
            const int pos = basep[b_[k]] + rk_[k];
            if (pos < CAPB)
                epackA[(size_t)b_[k] * CAPB + pos] = make_int2(pk_[k], vv_[k]);
        }
    }
}

__global__ __launch_bounds__(256) void bucket_build(const int* __restrict__ cursorA,
                                                    const int2* __restrict__ epackA,
                                                    int2* __restrict__ rowmeta,
                                                    int2* __restrict__ epackB) {
    __shared__ int cnt[BROWS2];
    __shared__ int excl[BROWS2];
    __shared__ int wsum[4];
    const int b = blockIdx.x;
    const int t = threadIdx.x;
    cnt[t] = 0;
    __syncthreads();

    const size_t sa = (size_t)b * CAPB;
    const int n = min(cursorA[b], CAPB);

    int pk_[KB], vv_[KB], rk_[KB];
#pragma unroll
    for (int k = 0; k < KB; ++k) {
        const int i = t + k * 256;
        rk_[k] = -1;
        if (i < n) {
            const int2 e = epackA[sa + i];
            pk_[k] = e.x;
            vv_[k] = e.y;
            rk_[k] = atomicAdd(&cnt[e.x >> 17], 1);
        }
    }
    __syncthreads();

    {
        const int lane = t & 63;
        const int my   = cnt[t];
        int x = my;
#pragma unroll
        for (int off = 1; off < 64; off <<= 1) {
            const int y = __shfl_up(x, off, 64);
            if (lane >= off) x += y;
        }
        if (lane == 63) wsum[t >> 6] = x;
        __syncthreads();
        int pre = x - my;
        const int w = t >> 6;
        for (int kk = 0; kk < w; ++kk) pre += wsum[kk];
        excl[t] = pre;
        const int r = b * BROWS2 + t;
        if (r < N_NODES) rowmeta[r] = make_int2((int)sa + pre, my);
    }
    __syncthreads();

#pragma unroll
    for (int k = 0; k < KB; ++k) {
        if (rk_[k] >= 0) {
            const int rl  = pk_[k] >> 17;
            const int pos = excl[rl] + rk_[k];
            epackB[sa + pos] = make_int2(pk_[k] & 0x1FFFF, vv_[k]);
        }
    }
}

// ---------------------------------------------------------------------------
// csr_gather — byte-identical to the 64us-measured r5 version.
// ---------------------------------------------------------------------------
__global__ __launch_bounds__(256) void csr_gather(const int2* __restrict__ rowmeta,
                                                  const int2* __restrict__ epackB,
                                                  const unsigned short* __restrict__ support,
                                                  const float* __restrict__ bias,
                                                  float* __restrict__ out) {
    const int t = threadIdx.x;
    const int g = t >> 5;
    const int l = t & 31;
    const int r = blockIdx.x * 8 + g;
    if (r >= N_NODES) return;

    const int2 rm   = rowmeta[r];
    const int start = rm.x;
    const int deg   = rm.y;

    float4 acc = *(const float4*)&bias[l * 4];

    int i = 0;
    for (; i + 4 <= deg; i += 4) {
        const int2 e0 = epackB[start + i + 0];
        const int2 e1 = epackB[start + i + 1];
        const int2 e2 = epackB[start + i + 2];
        const int2 e3 = epackB[start + i + 3];
        const ushort4 u0 = *(const ushort4*)&support[(size_t)e0.x * OUT_F + l * 4];
        const ushort4 u1 = *(const ushort4*)&support[(size_t)e1.x * OUT_F + l * 4];
        const ushort4 u2 = *(const ushort4*)&support[(size_t)e2.x * OUT_F + l * 4];
        const ushort4 u3 = *(const ushort4*)&support[(size_t)e3.x * OUT_F + l * 4];
        const float v0 = __int_as_float(e0.y);
        const float v1 = __int_as_float(e1.y);
        const float v2 = __int_as_float(e2.y);
        const float v3 = __int_as_float(e3.y);
        acc.x = fmaf(v0, bf2f(u0.x), fmaf(v1, bf2f(u1.x), fmaf(v2, bf2f(u2.x), fmaf(v3, bf2f(u3.x), acc.x))));
        acc.y = fmaf(v0, bf2f(u0.y), fmaf(v1, bf2f(u1.y), fmaf(v2, bf2f(u2.y), fmaf(v3, bf2f(u3.y), acc.y))));
        acc.z = fmaf(v0, bf2f(u0.z), fmaf(v1, bf2f(u1.z), fmaf(v2, bf2f(u2.z), fmaf(v3, bf2f(u3.z), acc.z))));
        acc.w = fmaf(v0, bf2f(u0.w), fmaf(v1, bf2f(u1.w), fmaf(v2, bf2f(u2.w), fmaf(v3, bf2f(u3.w), acc.w))));
    }
    for (; i < deg; ++i) {
        const int2 e = epackB[start + i];
        const ushort4 u = *(const ushort4*)&support[(size_t)e.x * OUT_F + l * 4];
        const float v = __int_as_float(e.y);
        acc.x = fmaf(v, bf2f(u.x), acc.x);
        acc.y = fmaf(v, bf2f(u.y), acc.y);
        acc.z = fmaf(v, bf2f(u.z), acc.z);
        acc.w = fmaf(v, bf2f(u.w), acc.w);
    }

    *(float4*)&out[(size_t)r * OUT_F + l * 4] = acc;
}

// ---------------------------------------------------------------------------
extern "C" void kernel_launch(void* const* d_in, const int* in_sizes, int n_in,
                              void* d_out, int out_size, void* d_ws, size_t ws_size,
                              hipStream_t stream) {
    const float* X    = (const float*)d_in[0];
    const int*   arow = (const int*)d_in[1];
    const int*   acol = (const int*)d_in[2];
    const float* aval = (const float*)d_in[3];
    const float* W    = (const float*)d_in[4];
    const float* bias = (const float*)d_in[5];
    float*       out  = (float*)d_out;

    // ws: support bf16 25.6MB | Wt 64KB | rowmeta int2[N] 800KB | cursorA 1.6KB
    //     | epackB int2[NB2*CAPB] 15.0MB        total ~41.5MB
    // epackA (15.0MB) lives in d_out: consumed in P3 before csr_gather
    // rewrites out.
    char* ws = (char*)d_ws;
    unsigned short* support = (unsigned short*)ws;  ws += (size_t)N_NODES * OUT_F * 2;
    unsigned short* Wt = (unsigned short*)ws;       ws += (size_t)IN_F * OUT_F * 2;
    int2* rowmeta = (int2*)ws;                      ws += (size_t)N_NODES * 8;
    int*  cursorA = (int*)ws;                       ws += ((NB2 + 7) & ~7) * 4;
    int2* epackB  = (int2*)ws;
    int2* epackA  = (int2*)d_out;

    // cooperative grid size: resident-blocks-per-CU x CU count (cached)
    static int coopGrid = -1;            // -1 unknown, 0 unsupported
    if (coopGrid == -1) {
        int perCU = 0, numCU = 0, dev = 0;
        if (hipGetDevice(&dev) == hipSuccess &&
            hipOccupancyMaxActiveBlocksPerMultiprocessor(
                &perCU, (const void*)mega, 256, 0) == hipSuccess && perCU >= 1 &&
            hipDeviceGetAttribute(&numCU, hipDeviceAttributeMultiprocessorCount,
                                  dev) == hipSuccess && numCU >= 1) {
            long g = (long)perCU * numCU;
            coopGrid = (int)(g > 2048 ? 2048 : g);
        } else {
            coopGrid = 0;
        }
    }

    bool coopOK = false;
    if (coopGrid > 0) {
        void* args[] = {(void*)&X, (void*)&arow, (void*)&acol, (void*)&aval,
                        (void*)&W, (void*)&support, (void*)&Wt, (void*)&cursorA,
                        (void*)&epackA, (void*)&rowmeta, (void*)&epackB};
        if (hipLaunchCooperativeKernel((const void*)mega, dim3(coopGrid),
                                       dim3(256), args, 0, stream) == hipSuccess) {
            coopOK = true;
        } else {
            (void)hipGetLastError();     // clear error state
            coopGrid = 0;                // don't retry next call
        }
    }

    if (!coopOK) {                        // r5-verified 4-kernel fallback
        wt_build<<<OUT_F, 256, 0, stream>>>(W, Wt, cursorA);
        gemm_mfma<<<NGEMM, 256, 0, stream>>>(X, Wt, support);
        partition_edges<<<NPARTC, 256, 0, stream>>>(arow, acol, aval, cursorA, epackA);
        bucket_build<<<NB2, 256, 0, stream>>>(cursorA, epackA, rowmeta, epackB);
    }

    csr_gather<<<(N_NODES + 7) / 8, 256, 0, stream>>>(
        rowmeta, epackB, support, bias, out);
}

// Round 8
// 289.705 us; speedup vs baseline: 1.5604x; 1.5604x over previous
//
#include <hip/hip_runtime.h>

#define N_NODES 100000
#define N_EDGES 1600000
#define IN_F    256
#define OUT_F   128

#define BROWS2   256                  // rows per bucket
#define NB2      391                  // ceil(N_NODES / 256)
#define CAPB     4800                 // slots/bucket (mean 4096, sigma 64 -> +11 sigma)
#define PART_EPB 4096                 // edges per partition block
#define KE       (PART_EPB / 256)     // 16 edges/thread in partition
#define KB       ((CAPB + 255) / 256) // 19 edges/thread in bucket build
#define NGEMM    1563                 // ceil(N_NODES / 64) gemm tiles

typedef __attribute__((ext_vector_type(8))) short   s16x8;   // 8 x bf16 (MFMA A/B frag)
typedef __attribute__((ext_vector_type(4))) float   f32x4;   // MFMA C/D frag
typedef __attribute__((ext_vector_type(8))) unsigned short u16x8;

__device__ __forceinline__ unsigned short f2bf(float f) {   // fp32 -> bf16 RNE
    unsigned u = __float_as_uint(f);
    u += 0x7FFFu + ((u >> 16) & 1u);
    return (unsigned short)(u >> 16);
}
__device__ __forceinline__ float bf2f(unsigned short h) {
    return __uint_as_float((unsigned)h << 16);
}

// async global->LDS DMA, 16B per lane. LDS dest = wave-uniform base + lane*16
// (m104/m108); global src is per-lane -> swizzles live on the SOURCE (m173).
__device__ __forceinline__ void gl_lds16(const void* g, void* l) {
    __builtin_amdgcn_global_load_lds((const __attribute__((address_space(1))) void*)g,
                                     (__attribute__((address_space(3))) void*)l,
                                     16, 0, 0);
}
// v_cvt_pk_bf16_f32: 2 f32 -> packed 2xbf16 (RNE, same rounding as f2bf)
__device__ __forceinline__ unsigned cvt_pk_bf16(float lo, float hi) {
    unsigned r;
    asm("v_cvt_pk_bf16_f32 %0, %1, %2" : "=v"(r) : "v"(lo), "v"(hi));
    return r;
}

// ---------------------------------------------------------------------------
// K0: Wt_sw blocked layout [k/8][n][8]: Wt_sw[(k>>3)*1024 + n*8 + (k&7)] =
// bf16(W[k][n]).  The per-K-step 8KB slab (4 kq rows) is CONTIGUOUS, so a
// linear global_load_lds image of it is directly fragment-readable with
// uniform bank load (start bank = f(tm&7) only; 8 accesses/bank = minimum).
// Also zeroes bucket cursors.
// ---------------------------------------------------------------------------
__global__ __launch_bounds__(256) void wt_build(const float* __restrict__ W,
                                                unsigned short* __restrict__ Wt,
                                                int* __restrict__ cursorA) {
    const int n = blockIdx.x;       // 0..127
    const int k = threadIdx.x;      // 0..255
    Wt[(k >> 3) * 1024 + n * 8 + (k & 7)] = f2bf(W[(size_t)k * OUT_F + n]);
    const int idx = blockIdx.x * 256 + threadIdx.x;
    if (idx < NB2) cursorA[idx] = 0;
}

// ---------------------------------------------------------------------------
// K1: support = bf16(X @ W), 64x128 tile, MFMA 16x16x32 (r5-verified frag map).
// v3: ALL staging via global_load_lds width-16 (zero staging VALU — fixes the
// 1.5e7 bank conflicts + VALU-bound staging measured r6/r7):
//  - As: fp32 X -> LDS [64][32]f32 (8KB/step), XOR chunk-swizzle on the global
//    source: LDS slot s holds chunk(r=s>>3, j=(s&7)^(r&7)); reader inverts.
//    fp32->bf16 at frag read via v_cvt_pk_bf16_f32 (RNE, identical to f2bf).
//  - Bs: 8KB/step linear from Wt_sw slab.
// LDS 17.4KB (As+Bs, Ct overlaid at epilogue) vs 32.8KB -> ~8 blocks/CU.
// ---------------------------------------------------------------------------
__global__ __launch_bounds__(256) void gemm_mfma(const float* __restrict__ X,
                                                 const unsigned short* __restrict__ Wt,
                                                 unsigned short* __restrict__ support) {
    __shared__ __align__(16) char smem[17408];
    unsigned short* Bs  = (unsigned short*)smem;          // [4][128][8] = 8192B
    float*          Asf = (float*)(smem + 8192);          // [512] 16B-chunks = 8192B
    unsigned short* Ct  = (unsigned short*)smem;          // epilogue overlay [64][136]

    const int t    = threadIdx.x;
    const int wid  = t >> 6;
    const int lane = t & 63;
    const int tm   = lane & 15;
    const int quad = lane >> 4;
    const int row0 = blockIdx.x * 64;

    // ---- per-lane DMA source addresses (hoisted; += per step) ----
    // A: issue i covers slots s = wid*128 + i*64 + lane
    const char* srcA[2];
    char*       dstA[2];
#pragma unroll
    for (int i = 0; i < 2; ++i) {
        const int s  = wid * 128 + i * 64 + lane;
        const int r  = s >> 3;
        const int jj = (s & 7) ^ (r & 7);
        const int gr = min(row0 + r, N_NODES - 1);      // clamp: OOB-safe, rows discarded
        srcA[i] = (const char*)X + (size_t)gr * (IN_F * 4) + jj * 16;
        dstA[i] = (char*)Asf + (size_t)(wid * 128 + i * 64) * 16;
    }
    // B: issue i covers 1KB chunk (wid*2 + i) of the 8KB step slab
    const char* srcB[2];
    char*       dstB[2];
#pragma unroll
    for (int i = 0; i < 2; ++i) {
        const int c1k = wid * 2 + i;
        srcB[i] = (const char*)Wt + (size_t)c1k * 1024 + lane * 16;
        dstB[i] = (char*)Bs + (size_t)c1k * 1024;
    }

    f32x4 acc[8];
#pragma unroll
    for (int c = 0; c < 8; ++c) acc[c] = (f32x4){0.f, 0.f, 0.f, 0.f};

    for (int ks = 0; ks < 8; ++ks) {            // K-step = 32 (kb = ks*32)
        gl_lds16(srcA[0], dstA[0]);
        gl_lds16(srcA[1], dstA[1]);
        gl_lds16(srcB[0], dstB[0]);
        gl_lds16(srcB[1], dstB[1]);
        srcA[0] += 128; srcA[1] += 128;         // next 32 floats of X row
        srcB[0] += 8192; srcB[1] += 8192;       // next Wt_sw slab
        __syncthreads();                        // drains vmcnt -> LDS ready

        // A frag: row r = wid*16+tm, chunks j = quad*2, quad*2+1 (inverse swz)
        const int r  = wid * 16 + tm;
        const int j0 = quad * 2;
        const float4 a0 = *(const float4*)&Asf[(r * 8 + (j0 ^ (r & 7))) * 4];
        const float4 a1 = *(const float4*)&Asf[(r * 8 + ((j0 + 1) ^ (r & 7))) * 4];
        union { s16x8 v; unsigned u[4]; } af;
        af.u[0] = cvt_pk_bf16(a0.x, a0.y);
        af.u[1] = cvt_pk_bf16(a0.z, a0.w);
        af.u[2] = cvt_pk_bf16(a1.x, a1.y);
        af.u[3] = cvt_pk_bf16(a1.z, a1.w);

#pragma unroll
        for (int c = 0; c < 8; ++c) {
            const s16x8 b = *(const s16x8*)&Bs[(quad * 128 + c * 16 + tm) * 8];
            acc[c] = __builtin_amdgcn_mfma_f32_16x16x32_bf16(af.v, b, acc[c], 0, 0, 0);
        }
        __syncthreads();                        // frag reads done before overwrite
    }

    // epilogue: regs -> LDS (bf16, Ct overlays As/Bs) -> coalesced global
#pragma unroll
    for (int c = 0; c < 8; ++c) {
        const int col = c * 16 + tm;
#pragma unroll
        for (int reg = 0; reg < 4; ++reg) {
            const int m = wid * 16 + quad * 4 + reg;
            Ct[m * 136 + col] = f2bf(acc[c][reg]);
        }
    }
    __syncthreads();
    {
        const int m   = t >> 2;
        const int seg = (t & 3) * 32;
        const int gr  = row0 + m;
        if (gr < N_NODES) {
            unsigned short* op = &support[(size_t)gr * OUT_F + seg];
#pragma unroll
            for (int i = 0; i < 4; ++i)
                *(u16x8*)(op + i * 8) = *(const u16x8*)&Ct[m * 136 + seg + i * 8];
        }
    }
}

// ---------------------------------------------------------------------------
// K2: partition edges into 391 coarse buckets (r5-verified, byte-identical).
// ---------------------------------------------------------------------------
__global__ __launch_bounds__(256) void partition_edges(const int* __restrict__ arow,
                                                       const int* __restrict__ acol,
                                                       const float* __restrict__ aval,
                                                       int* __restrict__ cursorA,
                                                       int2* __restrict__ epackA) {
    __shared__ int cnt[NB2];
    __shared__ int basep[NB2];
    const int t = threadIdx.x;
    for (int k = t; k < NB2; k += 256) cnt[k] = 0;
    __syncthreads();

    const int base = blockIdx.x * PART_EPB;
    int pk_[KE], vv_[KE], b_[KE], rk_[KE];
#pragma unroll
    for (int k = 0; k < KE; ++k) {
        const int i = base + t + k * 256;
        b_[k] = -1;
        if (i < N_EDGES) {
            const int r = arow[i];
            b_[k]  = r >> 8;
            pk_[k] = ((r & (BROWS2 - 1)) << 17) | acol[i];
            vv_[k] = __float_as_int(aval[i]);
            rk_[k] = atomicAdd(&cnt[b_[k]], 1);
        }
    }
    __syncthreads();
    for (int k = t; k < NB2; k += 256) {
        const int c = cnt[k];
        if (c > 0) basep[k] = atomicAdd(&cursorA[k], c);
    }
    __syncthreads();
#pragma unroll
    for (int k = 0; k < KE; ++k) {
        if (b_[k] >= 0) {
            const int pos = basep[b_[k]] + rk_[k];
            if (pos < CAPB)
                epackA[(size_t)b_[k] * CAPB + pos] = make_int2(pk_[k], vv_[k]);
        }
    }
}

// ---------------------------------------------------------------------------
// K3: per-bucket exact CSR build (r5-verified, byte-identical).
// ---------------------------------------------------------------------------
__global__ __launch_bounds__(256) void bucket_build(const int* __restrict__ cursorA,
                                                    const int2* __restrict__ epackA,
                                                    int2* __restrict__ rowmeta,
                                                    int2* __restrict__ epackB) {
    __shared__ int cnt[BROWS2];
    __shared__ int excl[BROWS2];
    __shared__ int wsum[4];
    const int b = blockIdx.x;
    const int t = threadIdx.x;
    cnt[t] = 0;
    __syncthreads();

    const size_t sa = (size_t)b * CAPB;
    const int n = min(cursorA[b], CAPB);

    int pk_[KB], vv_[KB], rk_[KB];
#pragma unroll
    for (int k = 0; k < KB; ++k) {
        const int i = t + k * 256;
        rk_[k] = -1;
        if (i < n) {
            const int2 e = epackA[sa + i];
            pk_[k] = e.x;
            vv_[k] = e.y;
            rk_[k] = atomicAdd(&cnt[e.x >> 17], 1);
        }
    }
    __syncthreads();

    {
        const int lane = t & 63;
        const int my   = cnt[t];
        int x = my;
#pragma unroll
        for (int off = 1; off < 64; off <<= 1) {
            const int y = __shfl_up(x, off, 64);
            if (lane >= off) x += y;
        }
        if (lane == 63) wsum[t >> 6] = x;
        __syncthreads();
        int pre = x - my;
        const int w = t >> 6;
        for (int kk = 0; kk < w; ++kk) pre += wsum[kk];
        excl[t] = pre;
        const int r = b * BROWS2 + t;
        if (r < N_NODES) rowmeta[r] = make_int2((int)sa + pre, my);
    }
    __syncthreads();

#pragma unroll
    for (int k = 0; k < KB; ++k) {
        if (rk_[k] >= 0) {
            const int rl  = pk_[k] >> 17;
            const int pos = excl[rl] + rk_[k];
            epackB[sa + pos] = make_int2(pk_[k] & 0x1FFFF, vv_[k]);
        }
    }
}

// ---------------------------------------------------------------------------
// K4: CSR gather — byte-identical to the 64us-measured r5 version.
// ---------------------------------------------------------------------------
__global__ __launch_bounds__(256) void csr_gather(const int2* __restrict__ rowmeta,
                                                  const int2* __restrict__ epackB,
                                                  const unsigned short* __restrict__ support,
                                                  const float* __restrict__ bias,
                                                  float* __restrict__ out) {
    const int t = threadIdx.x;
    const int g = t >> 5;
    const int l = t & 31;
    const int r = blockIdx.x * 8 + g;
    if (r >= N_NODES) return;

    const int2 rm   = rowmeta[r];
    const int start = rm.x;
    const int deg   = rm.y;

    float4 acc = *(const float4*)&bias[l * 4];

    int i = 0;
    for (; i + 4 <= deg; i += 4) {
        const int2 e0 = epackB[start + i + 0];
        const int2 e1 = epackB[start + i + 1];
        const int2 e2 = epackB[start + i + 2];
        const int2 e3 = epackB[start + i + 3];
        const ushort4 u0 = *(const ushort4*)&support[(size_t)e0.x * OUT_F + l * 4];
        const ushort4 u1 = *(const ushort4*)&support[(size_t)e1.x * OUT_F + l * 4];
        const ushort4 u2 = *(const ushort4*)&support[(size_t)e2.x * OUT_F + l * 4];
        const ushort4 u3 = *(const ushort4*)&support[(size_t)e3.x * OUT_F + l * 4];
        const float v0 = __int_as_float(e0.y);
        const float v1 = __int_as_float(e1.y);
        const float v2 = __int_as_float(e2.y);
        const float v3 = __int_as_float(e3.y);
        acc.x = fmaf(v0, bf2f(u0.x), fmaf(v1, bf2f(u1.x), fmaf(v2, bf2f(u2.x), fmaf(v3, bf2f(u3.x), acc.x))));
        acc.y = fmaf(v0, bf2f(u0.y), fmaf(v1, bf2f(u1.y), fmaf(v2, bf2f(u2.y), fmaf(v3, bf2f(u3.y), acc.y))));
        acc.z = fmaf(v0, bf2f(u0.z), fmaf(v1, bf2f(u1.z), fmaf(v2, bf2f(u2.z), fmaf(v3, bf2f(u3.z), acc.z))));
        acc.w = fmaf(v0, bf2f(u0.w), fmaf(v1, bf2f(u1.w), fmaf(v2, bf2f(u2.w), fmaf(v3, bf2f(u3.w), acc.w))));
    }
    for (; i < deg; ++i) {
        const int2 e = epackB[start + i];
        const ushort4 u = *(const ushort4*)&support[(size_t)e.x * OUT_F + l * 4];
        const float v = __int_as_float(e.y);
        acc.x = fmaf(v, bf2f(u.x), acc.x);
        acc.y = fmaf(v, bf2f(u.y), acc.y);
        acc.z = fmaf(v, bf2f(u.z), acc.z);
        acc.w = fmaf(v, bf2f(u.w), acc.w);
    }

    *(float4*)&out[(size_t)r * OUT_F + l * 4] = acc;
}

// ---------------------------------------------------------------------------
extern "C" void kernel_launch(void* const* d_in, const int* in_sizes, int n_in,
                              void* d_out, int out_size, void* d_ws, size_t ws_size,
                              hipStream_t stream) {
    const float* X    = (const float*)d_in[0];
    const int*   arow = (const int*)d_in[1];
    const int*   acol = (const int*)d_in[2];
    const float* aval = (const float*)d_in[3];
    const float* W    = (const float*)d_in[4];
    const float* bias = (const float*)d_in[5];
    float*       out  = (float*)d_out;

    // ws: support bf16 25.6MB | Wt_sw 64KB | rowmeta int2[N] 800KB | cursorA
    //     1.6KB | epackB int2[NB2*CAPB] 15.0MB       total ~41.5MB
    // epackA (15.0MB) lives in d_out: consumed by bucket_build before
    // csr_gather rewrites out.  (All carve offsets 16B-aligned.)
    char* ws = (char*)d_ws;
    unsigned short* support = (unsigned short*)ws;  ws += (size_t)N_NODES * OUT_F * 2;
    unsigned short* Wt = (unsigned short*)ws;       ws += (size_t)IN_F * OUT_F * 2;
    int2* rowmeta = (int2*)ws;                      ws += (size_t)N_NODES * 8;
    int*  cursorA = (int*)ws;                       ws += ((NB2 + 7) & ~7) * 4;
    int2* epackB  = (int2*)ws;
    int2* epackA  = (int2*)d_out;

    wt_build<<<OUT_F, 256, 0, stream>>>(W, Wt, cursorA);
    gemm_mfma<<<NGEMM, 256, 0, stream>>>(X, Wt, support);
    partition_edges<<<(N_EDGES + PART_EPB - 1) / PART_EPB, 256, 0, stream>>>(
        arow, acol, aval, cursorA, epackA);
    bucket_build<<<NB2, 256, 0, stream>>>(cursorA, epackA, rowmeta, epackB);
    csr_gather<<<(N_NODES + 7) / 8, 256, 0, stream>>>(
        rowmeta, epackB, support, bias, out);
}

// Round 9
// 286.967 us; speedup vs baseline: 1.5753x; 1.0095x over previous
//
#include <hip/hip_runtime.h>

#define N_NODES 100000
#define N_EDGES 1600000
#define IN_F    256
#define OUT_F   128

#define BROWS    64                   // rows per bucket
#define NB       1563                 // ceil(N_NODES / 64)
#define CAP      1312                 // slots/bucket (mean 1024, sigma 32 -> +9 sigma)
#define PART_EPB 4096                 // edges per partition block (391 blocks)
#define KE       (PART_EPB / 256)     // 16 edges/thread in partition
#define KB2      6                    // ceil(CAP / 256) edges/thread in stage
#define NGEMM    1563                 // ceil(N_NODES / 64) gemm tiles

typedef __attribute__((ext_vector_type(8))) short   s16x8;   // 8 x bf16 (MFMA A/B frag)
typedef __attribute__((ext_vector_type(4))) float   f32x4;   // MFMA C/D frag
typedef __attribute__((ext_vector_type(8))) unsigned short u16x8;

__device__ __forceinline__ unsigned short f2bf(float f) {   // fp32 -> bf16 RNE
    unsigned u = __float_as_uint(f);
    u += 0x7FFFu + ((u >> 16) & 1u);
    return (unsigned short)(u >> 16);
}
__device__ __forceinline__ float bf2f(unsigned short h) {
    return __uint_as_float((unsigned)h << 16);
}

// async global->LDS DMA, 16B per lane (r8-verified)
__device__ __forceinline__ void gl_lds16(const void* g, void* l) {
    __builtin_amdgcn_global_load_lds((const __attribute__((address_space(1))) void*)g,
                                     (__attribute__((address_space(3))) void*)l,
                                     16, 0, 0);
}
__device__ __forceinline__ unsigned cvt_pk_bf16(float lo, float hi) {
    unsigned r;
    asm("v_cvt_pk_bf16_f32 %0, %1, %2" : "=v"(r) : "v"(lo), "v"(hi));
    return r;
}

// ---------------------------------------------------------------------------
// K0: Wt_sw blocked layout [k/8][n][8] (r8-verified) + zero bucket cursors.
// ---------------------------------------------------------------------------
__global__ __launch_bounds__(256) void wt_build(const float* __restrict__ W,
                                                unsigned short* __restrict__ Wt,
                                                int* __restrict__ cursorA) {
    const int n = blockIdx.x;       // 0..127
    const int k = threadIdx.x;      // 0..255
    Wt[(k >> 3) * 1024 + n * 8 + (k & 7)] = f2bf(W[(size_t)k * OUT_F + n]);
    const int idx = blockIdx.x * 256 + threadIdx.x;
    if (idx < NB) cursorA[idx] = 0;
}

// ---------------------------------------------------------------------------
// K1: support = bf16(X @ W) — r8-verified global_load_lds version, verbatim.
// ---------------------------------------------------------------------------
__global__ __launch_bounds__(256) void gemm_mfma(const float* __restrict__ X,
                                                 const unsigned short* __restrict__ Wt,
                                                 unsigned short* __restrict__ support) {
    __shared__ __align__(16) char smem[17408];
    unsigned short* Bs  = (unsigned short*)smem;          // [4][128][8] = 8192B
    float*          Asf = (float*)(smem + 8192);          // [512] 16B-chunks = 8192B
    unsigned short* Ct  = (unsigned short*)smem;          // epilogue overlay [64][136]

    const int t    = threadIdx.x;
    const int wid  = t >> 6;
    const int lane = t & 63;
    const int tm   = lane & 15;
    const int quad = lane >> 4;
    const int row0 = blockIdx.x * 64;

    const char* srcA[2];
    char*       dstA[2];
#pragma unroll
    for (int i = 0; i < 2; ++i) {
        const int s  = wid * 128 + i * 64 + lane;
        const int r  = s >> 3;
        const int jj = (s & 7) ^ (r & 7);
        const int gr = min(row0 + r, N_NODES - 1);
        srcA[i] = (const char*)X + (size_t)gr * (IN_F * 4) + jj * 16;
        dstA[i] = (char*)Asf + (size_t)(wid * 128 + i * 64) * 16;
    }
    const char* srcB[2];
    char*       dstB[2];
#pragma unroll
    for (int i = 0; i < 2; ++i) {
        const int c1k = wid * 2 + i;
        srcB[i] = (const char*)Wt + (size_t)c1k * 1024 + lane * 16;
        dstB[i] = (char*)Bs + (size_t)c1k * 1024;
    }

    f32x4 acc[8];
#pragma unroll
    for (int c = 0; c < 8; ++c) acc[c] = (f32x4){0.f, 0.f, 0.f, 0.f};

    for (int ks = 0; ks < 8; ++ks) {
        gl_lds16(srcA[0], dstA[0]);
        gl_lds16(srcA[1], dstA[1]);
        gl_lds16(srcB[0], dstB[0]);
        gl_lds16(srcB[1], dstB[1]);
        srcA[0] += 128; srcA[1] += 128;
        srcB[0] += 8192; srcB[1] += 8192;
        __syncthreads();

        const int r  = wid * 16 + tm;
        const int j0 = quad * 2;
        const float4 a0 = *(const float4*)&Asf[(r * 8 + (j0 ^ (r & 7))) * 4];
        const float4 a1 = *(const float4*)&Asf[(r * 8 + ((j0 + 1) ^ (r & 7))) * 4];
        union { s16x8 v; unsigned u[4]; } af;
        af.u[0] = cvt_pk_bf16(a0.x, a0.y);
        af.u[1] = cvt_pk_bf16(a0.z, a0.w);
        af.u[2] = cvt_pk_bf16(a1.x, a1.y);
        af.u[3] = cvt_pk_bf16(a1.z, a1.w);

#pragma unroll
        for (int c = 0; c < 8; ++c) {
            const s16x8 b = *(const s16x8*)&Bs[(quad * 128 + c * 16 + tm) * 8];
            acc[c] = __builtin_amdgcn_mfma_f32_16x16x32_bf16(af.v, b, acc[c], 0, 0, 0);
        }
        __syncthreads();
    }

#pragma unroll
    for (int c = 0; c < 8; ++c) {
        const int col = c * 16 + tm;
#pragma unroll
        for (int reg = 0; reg < 4; ++reg) {
            const int m = wid * 16 + quad * 4 + reg;
            Ct[m * 136 + col] = f2bf(acc[c][reg]);
        }
    }
    __syncthreads();
    {
        const int m   = t >> 2;
        const int seg = (t & 3) * 32;
        const int gr  = row0 + m;
        if (gr < N_NODES) {
            unsigned short* op = &support[(size_t)gr * OUT_F + seg];
#pragma unroll
            for (int i = 0; i < 4; ++i)
                *(u16x8*)(op + i * 8) = *(const u16x8*)&Ct[m * 136 + seg + i * 8];
        }
    }
}

// ---------------------------------------------------------------------------
// K2: partition edges into 1563 fine buckets (64 rows each). Same r5-verified
// structure; bucket = row >> 6. Known cost: per-bucket runs shrink to ~2.6
// edges -> ~3x write amp on the 12.8MB payload (~+4us) — accepted, enables
// the LDS-resident merged gather.
// ---------------------------------------------------------------------------
__global__ __launch_bounds__(256) void partition_edges(const int* __restrict__ arow,
                                                       const int* __restrict__ acol,
                                                       const float* __restrict__ aval,
                                                       int* __restrict__ cursorA,
                                                       int2* __restrict__ epackA) {
    __shared__ int cnt[NB];
    __shared__ int basep[NB];
    const int t = threadIdx.x;
    for (int k = t; k < NB; k += 256) cnt[k] = 0;
    __syncthreads();

    const int base = blockIdx.x * PART_EPB;
    int pk_[KE], vv_[KE], b_[KE], rk_[KE];
#pragma unroll
    for (int k = 0; k < KE; ++k) {
        const int i = base + t + k * 256;
        b_[k] = -1;
        if (i < N_EDGES) {
            const int r = arow[i];
            b_[k]  = r >> 6;
            pk_[k] = ((r & (BROWS - 1)) << 17) | acol[i];
            vv_[k] = __float_as_int(aval[i]);
            rk_[k] = atomicAdd(&cnt[b_[k]], 1);       // LDS int atomic, 1/edge
        }
    }
    __syncthreads();
    for (int k = t; k < NB; k += 256) {
        const int c = cnt[k];
        if (c > 0) basep[k] = atomicAdd(&cursorA[k], c);
    }
    __syncthreads();
#pragma unroll
    for (int k = 0; k < KE; ++k) {
        if (b_[k] >= 0) {
            const int pos = basep[b_[k]] + rk_[k];
            if (pos < CAP)       // 9-sigma guard
                epackA[(size_t)b_[k] * CAP + pos] = make_int2(pk_[k], vv_[k]);
        }
    }
}

// ---------------------------------------------------------------------------
// K3: MERGED bucket-CSR + gather (replaces bucket_build + csr_gather +
// rowmeta + epackB). One block per 64-row bucket:
//  Phase A: stage the bucket's unordered edges from epackA, row-rank them
//    (1 LDS int-atomic/edge, payload in static reg arrays), 64-entry wave
//    scan, ranked write into LDS eb[] — the per-bucket CSR never touches HBM.
//  Phase B: 8 groups x 32 lanes; group g gathers rows g*8..g*8+7 with the
//    r5-verified 4-edge-ILP support-gather loop, edges read from LDS
//    (uniform per group -> broadcast, conflict-free).
// Deletes: epackB 25.6MB RT, rowmeta 1.6MB RT, one launch + full-grid drain.
// 1563 blocks, ~11KB LDS, wave-capped 8 blocks/CU -> all co-resident (~75%).
// ---------------------------------------------------------------------------
__global__ __launch_bounds__(256) void bucket_gather(const int* __restrict__ cursorA,
                                                     const int2* __restrict__ epackA,
                                                     const unsigned short* __restrict__ support,
                                                     const float* __restrict__ bias,
                                                     float* __restrict__ out) {
    __shared__ int2 eb[CAP];          // row-ranked bucket edges (10.5 KB)
    __shared__ int  cnt[BROWS];
    __shared__ int  excl[BROWS];

    const int b = blockIdx.x;
    const int t = threadIdx.x;

    if (t < BROWS) cnt[t] = 0;
    __syncthreads();

    const size_t sa = (size_t)b * CAP;
    const int n = min(cursorA[b], CAP);

    // ---- Phase A: stage + rank ----
    int pk_[KB2], vv_[KB2], rk_[KB2];
#pragma unroll
    for (int k = 0; k < KB2; ++k) {
        const int i = t + k * 256;
        rk_[k] = -1;
        if (i < n) {
            const int2 e = epackA[sa + i];
            pk_[k] = e.x;
            vv_[k] = e.y;
            rk_[k] = atomicAdd(&cnt[e.x >> 17], 1);   // LDS int atomic
        }
    }
    __syncthreads();

    if (t < BROWS) {                   // 64-entry exclusive scan, wave 0
        const int my = cnt[t];
        int x = my;
#pragma unroll
        for (int off = 1; off < 64; off <<= 1) {
            const int y = __shfl_up(x, off, 64);
            if (t >= off) x += y;
        }
        excl[t] = x - my;
    }
    __syncthreads();

#pragma unroll
    for (int k = 0; k < KB2; ++k) {
        if (rk_[k] >= 0) {
            const int rl = pk_[k] >> 17;
            eb[excl[rl] + rk_[k]] = make_int2(pk_[k] & 0x1FFFF, vv_[k]);
        }
    }
    __syncthreads();

    // ---- Phase B: gather (r5-verified inner loop; edges now from LDS) ----
    const int g = t >> 5;              // group 0..7
    const int l = t & 31;              // lane in group
    const float4 bv = *(const float4*)&bias[l * 4];

    for (int rr = 0; rr < 8; ++rr) {
        const int rl = g * 8 + rr;
        const int r  = b * BROWS + rl;
        if (r >= N_NODES) continue;    // uniform per group; no barriers below

        const int start = excl[rl];
        const int deg   = cnt[rl];
        float4 acc = bv;

        int i = 0;
        for (; i + 4 <= deg; i += 4) {
            const int2 e0 = eb[start + i + 0];
            const int2 e1 = eb[start + i + 1];
            const int2 e2 = eb[start + i + 2];
            const int2 e3 = eb[start + i + 3];
            const ushort4 u0 = *(const ushort4*)&support[(size_t)e0.x * OUT_F + l * 4];
            const ushort4 u1 = *(const ushort4*)&support[(size_t)e1.x * OUT_F + l * 4];
            const ushort4 u2 = *(const ushort4*)&support[(size_t)e2.x * OUT_F + l * 4];
            const ushort4 u3 = *(const ushort4*)&support[(size_t)e3.x * OUT_F + l * 4];
            const float v0 = __int_as_float(e0.y);
            const float v1 = __int_as_float(e1.y);
            const float v2 = __int_as_float(e2.y);
            const float v3 = __int_as_float(e3.y);
            acc.x = fmaf(v0, bf2f(u0.x), fmaf(v1, bf2f(u1.x), fmaf(v2, bf2f(u2.x), fmaf(v3, bf2f(u3.x), acc.x))));
            acc.y = fmaf(v0, bf2f(u0.y), fmaf(v1, bf2f(u1.y), fmaf(v2, bf2f(u2.y), fmaf(v3, bf2f(u3.y), acc.y))));
            acc.z = fmaf(v0, bf2f(u0.z), fmaf(v1, bf2f(u1.z), fmaf(v2, bf2f(u2.z), fmaf(v3, bf2f(u3.z), acc.z))));
            acc.w = fmaf(v0, bf2f(u0.w), fmaf(v1, bf2f(u1.w), fmaf(v2, bf2f(u2.w), fmaf(v3, bf2f(u3.w), acc.w))));
        }
        for (; i < deg; ++i) {
            const int2 e = eb[start + i];
            const ushort4 u = *(const ushort4*)&support[(size_t)e.x * OUT_F + l * 4];
            const float v = __int_as_float(e.y);
            acc.x = fmaf(v, bf2f(u.x), acc.x);
            acc.y = fmaf(v, bf2f(u.y), acc.y);
            acc.z = fmaf(v, bf2f(u.z), acc.z);
            acc.w = fmaf(v, bf2f(u.w), acc.w);
        }

        *(float4*)&out[(size_t)r * OUT_F + l * 4] = acc;
    }
}

// ---------------------------------------------------------------------------
extern "C" void kernel_launch(void* const* d_in, const int* in_sizes, int n_in,
                              void* d_out, int out_size, void* d_ws, size_t ws_size,
                              hipStream_t stream) {
    const float* X    = (const float*)d_in[0];
    const int*   arow = (const int*)d_in[1];
    const int*   acol = (const int*)d_in[2];
    const float* aval = (const float*)d_in[3];
    const float* W    = (const float*)d_in[4];
    const float* bias = (const float*)d_in[5];
    float*       out  = (float*)d_out;

    // ws: support bf16 25.6MB | Wt_sw 64KB | cursorA 6.3KB
    //     | epackA int2[NB*CAP] 16.4MB            total ~42.1MB
    // epackB / rowmeta deleted; d_out written only by bucket_gather.
    char* ws = (char*)d_ws;
    unsigned short* support = (unsigned short*)ws;  ws += (size_t)N_NODES * OUT_F * 2;
    unsigned short* Wt = (unsigned short*)ws;       ws += (size_t)IN_F * OUT_F * 2;
    int*  cursorA = (int*)ws;                       ws += ((NB + 7) & ~7) * 4;
    int2* epackA  = (int2*)ws;

    wt_build<<<OUT_F, 256, 0, stream>>>(W, Wt, cursorA);
    gemm_mfma<<<NGEMM, 256, 0, stream>>>(X, Wt, support);
    partition_edges<<<(N_EDGES + PART_EPB - 1) / PART_EPB, 256, 0, stream>>>(
        arow, acol, aval, cursorA, epackA);
    bucket_gather<<<NB, 256, 0, stream>>>(cursorA, epackA, support, bias, out);
}

// Round 10
// 278.114 us; speedup vs baseline: 1.6255x; 1.0318x over previous
//
#include <hip/hip_runtime.h>

#define N_NODES 100000
#define N_EDGES 1600000
#define IN_F    256
#define OUT_F   128

#define BROWS    64                   // rows per bucket
#define NB       1563                 // ceil(N_NODES / 64)
#define CAP      1312                 // slots/bucket (mean 1024, sigma 32 -> +9 sigma)
#define PART_EPB 4096                 // edges per partition-role block
#define NPARTB   391                  // ceil(N_EDGES / PART_EPB)
#define KE       (PART_EPB / 256)     // 16 edges/thread in partition role
#define KB2      6                    // ceil(CAP / 256) edges/thread in gather stage
#define NGEMM    1563                 // ceil(N_NODES / 64) gemm tiles
#define NFUSED   (NGEMM + NPARTB)     // 1954

typedef __attribute__((ext_vector_type(8))) short   s16x8;   // 8 x bf16 (MFMA A/B frag)
typedef __attribute__((ext_vector_type(4))) float   f32x4;   // MFMA C/D frag
typedef __attribute__((ext_vector_type(8))) unsigned short u16x8;

__device__ __forceinline__ unsigned short f2bf(float f) {   // fp32 -> bf16 RNE
    unsigned u = __float_as_uint(f);
    u += 0x7FFFu + ((u >> 16) & 1u);
    return (unsigned short)(u >> 16);
}
__device__ __forceinline__ float bf2f(unsigned short h) {
    return __uint_as_float((unsigned)h << 16);
}

// async global->LDS DMA, 16B per lane (r8-verified)
__device__ __forceinline__ void gl_lds16(const void* g, void* l) {
    __builtin_amdgcn_global_load_lds((const __attribute__((address_space(1))) void*)g,
                                     (__attribute__((address_space(3))) void*)l,
                                     16, 0, 0);
}
__device__ __forceinline__ unsigned cvt_pk_bf16(float lo, float hi) {
    unsigned r;
    asm("v_cvt_pk_bf16_f32 %0, %1, %2" : "=v"(r) : "v"(lo), "v"(hi));
    return r;
}

// ---------------------------------------------------------------------------
// K0: Wt_sw blocked layout [k/8][n][8] (r8-verified) + zero bucket cursors.
// ---------------------------------------------------------------------------
__global__ __launch_bounds__(256) void wt_build(const float* __restrict__ W,
                                                unsigned short* __restrict__ Wt,
                                                int* __restrict__ cursorA) {
    const int n = blockIdx.x;       // 0..127
    const int k = threadIdx.x;      // 0..255
    Wt[(k >> 3) * 1024 + n * 8 + (k & 7)] = f2bf(W[(size_t)k * OUT_F + n]);
    const int idx = blockIdx.x * 256 + threadIdx.x;
    if (idx < NB) cursorA[idx] = 0;
}

// ---------------------------------------------------------------------------
// K1: FUSED gemm + partition, INTERLEAVED roles (r6 lesson: contiguous role
// ranges dispatch serially — partition filled the machine, then gemm; 104us =
// exact sum. Here every 5th block is partition (391 of 1954), so the initial
// residency wave holds BOTH roles and partition's memory/atomic latency hides
// under gemm's MFMA work).
//   bid % 5 == 0 -> partition block pid = bid/5      (r9 body, KE=16)
//   else         -> gemm tile    gid = bid - bid/5 - 1 (r8 DMA body)
// Union LDS 17.4KB (vs r6's 33KB) -> both roles co-resident at ~5 blocks/CU.
// ---------------------------------------------------------------------------
__global__ __launch_bounds__(256) void fused_gp2(const float* __restrict__ X,
                                                 const unsigned short* __restrict__ Wt,
                                                 unsigned short* __restrict__ support,
                                                 const int* __restrict__ arow,
                                                 const int* __restrict__ acol,
                                                 const float* __restrict__ aval,
                                                 int* __restrict__ cursorA,
                                                 int2* __restrict__ epackA) {
    __shared__ __align__(16) char smem[17408];
    const int t   = threadIdx.x;
    const int bid = blockIdx.x;

    if (bid % 5 == 0) {
        // ---------------- partition role (pid = bid/5, 0..390) ------------
        int* cnt   = (int*)smem;          // [NB]  6252B
        int* basep = cnt + NB;            // [NB]  (12504B total <= 17408)
        for (int k = t; k < NB; k += 256) cnt[k] = 0;
        __syncthreads();

        const int base = (bid / 5) * PART_EPB;
        int pk_[KE], vv_[KE], b_[KE], rk_[KE];
#pragma unroll
        for (int k = 0; k < KE; ++k) {
            const int i = base + t + k * 256;
            b_[k] = -1;
            if (i < N_EDGES) {
                const int r = arow[i];
                b_[k]  = r >> 6;
                pk_[k] = ((r & (BROWS - 1)) << 17) | acol[i];
                vv_[k] = __float_as_int(aval[i]);
                rk_[k] = atomicAdd(&cnt[b_[k]], 1);      // LDS int atomic, 1/edge
            }
        }
        __syncthreads();
        for (int k = t; k < NB; k += 256) {
            const int c = cnt[k];
            if (c > 0) basep[k] = atomicAdd(&cursorA[k], c);
        }
        __syncthreads();
#pragma unroll
        for (int k = 0; k < KE; ++k) {
            if (b_[k] >= 0) {
                const int pos = basep[b_[k]] + rk_[k];
                if (pos < CAP)       // 9-sigma guard
                    epackA[(size_t)b_[k] * CAP + pos] = make_int2(pk_[k], vv_[k]);
            }
        }
        return;
    }

    // ---------------- gemm role (gid = bid - bid/5 - 1, 0..1562) ----------
    unsigned short* Bs  = (unsigned short*)smem;          // [4][128][8] = 8192B
    float*          Asf = (float*)(smem + 8192);          // [512] 16B-chunks = 8192B
    unsigned short* Ct  = (unsigned short*)smem;          // epilogue overlay [64][136]

    const int wid  = t >> 6;
    const int lane = t & 63;
    const int tm   = lane & 15;
    const int quad = lane >> 4;
    const int row0 = (bid - bid / 5 - 1) * 64;

    const char* srcA[2];
    char*       dstA[2];
#pragma unroll
    for (int i = 0; i < 2; ++i) {
        const int s  = wid * 128 + i * 64 + lane;
        const int r  = s >> 3;
        const int jj = (s & 7) ^ (r & 7);
        const int gr = min(row0 + r, N_NODES - 1);
        srcA[i] = (const char*)X + (size_t)gr * (IN_F * 4) + jj * 16;
        dstA[i] = (char*)Asf + (size_t)(wid * 128 + i * 64) * 16;
    }
    const char* srcB[2];
    char*       dstB[2];
#pragma unroll
    for (int i = 0; i < 2; ++i) {
        const int c1k = wid * 2 + i;
        srcB[i] = (const char*)Wt + (size_t)c1k * 1024 + lane * 16;
        dstB[i] = (char*)Bs + (size_t)c1k * 1024;
    }

    f32x4 acc[8];
#pragma unroll
    for (int c = 0; c < 8; ++c) acc[c] = (f32x4){0.f, 0.f, 0.f, 0.f};

    for (int ks = 0; ks < 8; ++ks) {
        gl_lds16(srcA[0], dstA[0]);
        gl_lds16(srcA[1], dstA[1]);
        gl_lds16(srcB[0], dstB[0]);
        gl_lds16(srcB[1], dstB[1]);
        srcA[0] += 128; srcA[1] += 128;
        srcB[0] += 8192; srcB[1] += 8192;
        __syncthreads();

        const int r  = wid * 16 + tm;
        const int j0 = quad * 2;
        const float4 a0 = *(const float4*)&Asf[(r * 8 + (j0 ^ (r & 7))) * 4];
        const float4 a1 = *(const float4*)&Asf[(r * 8 + ((j0 + 1) ^ (r & 7))) * 4];
        union { s16x8 v; unsigned u[4]; } af;
        af.u[0] = cvt_pk_bf16(a0.x, a0.y);
        af.u[1] = cvt_pk_bf16(a0.z, a0.w);
        af.u[2] = cvt_pk_bf16(a1.x, a1.y);
        af.u[3] = cvt_pk_bf16(a1.z, a1.w);

#pragma unroll
        for (int c = 0; c < 8; ++c) {
            const s16x8 b = *(const s16x8*)&Bs[(quad * 128 + c * 16 + tm) * 8];
            acc[c] = __builtin_amdgcn_mfma_f32_16x16x32_bf16(af.v, b, acc[c], 0, 0, 0);
        }
        __syncthreads();
    }

#pragma unroll
    for (int c = 0; c < 8; ++c) {
        const int col = c * 16 + tm;
#pragma unroll
        for (int reg = 0; reg < 4; ++reg) {
            const int m = wid * 16 + quad * 4 + reg;
            Ct[m * 136 + col] = f2bf(acc[c][reg]);
        }
    }
    __syncthreads();
    {
        const int m   = t >> 2;
        const int seg = (t & 3) * 32;
        const int gr  = row0 + m;
        if (gr < N_NODES) {
            unsigned short* op = &support[(size_t)gr * OUT_F + seg];
#pragma unroll
            for (int i = 0; i < 4; ++i)
                *(u16x8*)(op + i * 8) = *(const u16x8*)&Ct[m * 136 + seg + i * 8];
        }
    }
}

// ---------------------------------------------------------------------------
// K2: MERGED bucket-CSR + gather (r9-verified, byte-identical; 67us @ 43.8%).
// ---------------------------------------------------------------------------
__global__ __launch_bounds__(256) void bucket_gather(const int* __restrict__ cursorA,
                                                     const int2* __restrict__ epackA,
                                                     const unsigned short* __restrict__ support,
                                                     const float* __restrict__ bias,
                                                     float* __restrict__ out) {
    __shared__ int2 eb[CAP];          // row-ranked bucket edges (10.5 KB)
    __shared__ int  cnt[BROWS];
    __shared__ int  excl[BROWS];

    const int b = blockIdx.x;
    const int t = threadIdx.x;

    if (t < BROWS) cnt[t] = 0;
    __syncthreads();

    const size_t sa = (size_t)b * CAP;
    const int n = min(cursorA[b], CAP);

    // ---- Phase A: stage + rank ----
    int pk_[KB2], vv_[KB2], rk_[KB2];
#pragma unroll
    for (int k = 0; k < KB2; ++k) {
        const int i = t + k * 256;
        rk_[k] = -1;
        if (i < n) {
            const int2 e = epackA[sa + i];
            pk_[k] = e.x;
            vv_[k] = e.y;
            rk_[k] = atomicAdd(&cnt[e.x >> 17], 1);   // LDS int atomic
        }
    }
    __syncthreads();

    if (t < BROWS) {                   // 64-entry exclusive scan, wave 0
        const int my = cnt[t];
        int x = my;
#pragma unroll
        for (int off = 1; off < 64; off <<= 1) {
            const int y = __shfl_up(x, off, 64);
            if (t >= off) x += y;
        }
        excl[t] = x - my;
    }
    __syncthreads();

#pragma unroll
    for (int k = 0; k < KB2; ++k) {
        if (rk_[k] >= 0) {
            const int rl = pk_[k] >> 17;
            eb[excl[rl] + rk_[k]] = make_int2(pk_[k] & 0x1FFFF, vv_[k]);
        }
    }
    __syncthreads();

    // ---- Phase B: gather (4-edge ILP; edges broadcast from LDS) ----
    const int g = t >> 5;              // group 0..7
    const int l = t & 31;              // lane in group
    const float4 bv = *(const float4*)&bias[l * 4];

    for (int rr = 0; rr < 8; ++rr) {
        const int rl = g * 8 + rr;
        const int r  = b * BROWS + rl;
        if (r >= N_NODES) continue;    // uniform per group; no barriers below

        const int start = excl[rl];
        const int deg   = cnt[rl];
        float4 acc = bv;

        int i = 0;
        for (; i + 4 <= deg; i += 4) {
            const int2 e0 = eb[start + i + 0];
            const int2 e1 = eb[start + i + 1];
            const int2 e2 = eb[start + i + 2];
            const int2 e3 = eb[start + i + 3];
            const ushort4 u0 = *(const ushort4*)&support[(size_t)e0.x * OUT_F + l * 4];
            const ushort4 u1 = *(const ushort4*)&support[(size_t)e1.x * OUT_F + l * 4];
            const ushort4 u2 = *(const ushort4*)&support[(size_t)e2.x * OUT_F + l * 4];
            const ushort4 u3 = *(const ushort4*)&support[(size_t)e3.x * OUT_F + l * 4];
            const float v0 = __int_as_float(e0.y);
            const float v1 = __int_as_float(e1.y);
            const float v2 = __int_as_float(e2.y);
            const float v3 = __int_as_float(e3.y);
            acc.x = fmaf(v0, bf2f(u0.x), fmaf(v1, bf2f(u1.x), fmaf(v2, bf2f(u2.x), fmaf(v3, bf2f(u3.x), acc.x))));
            acc.y = fmaf(v0, bf2f(u0.y), fmaf(v1, bf2f(u1.y), fmaf(v2, bf2f(u2.y), fmaf(v3, bf2f(u3.y), acc.y))));
            acc.z = fmaf(v0, bf2f(u0.z), fmaf(v1, bf2f(u1.z), fmaf(v2, bf2f(u2.z), fmaf(v3, bf2f(u3.z), acc.z))));
            acc.w = fmaf(v0, bf2f(u0.w), fmaf(v1, bf2f(u1.w), fmaf(v2, bf2f(u2.w), fmaf(v3, bf2f(u3.w), acc.w))));
        }
        for (; i < deg; ++i) {
            const int2 e = eb[start + i];
            const ushort4 u = *(const ushort4*)&support[(size_t)e.x * OUT_F + l * 4];
            const float v = __int_as_float(e.y);
            acc.x = fmaf(v, bf2f(u.x), acc.x);
            acc.y = fmaf(v, bf2f(u.y), acc.y);
            acc.z = fmaf(v, bf2f(u.z), acc.z);
            acc.w = fmaf(v, bf2f(u.w), acc.w);
        }

        *(float4*)&out[(size_t)r * OUT_F + l * 4] = acc;
    }
}

// ---------------------------------------------------------------------------
extern "C" void kernel_launch(void* const* d_in, const int* in_sizes, int n_in,
                              void* d_out, int out_size, void* d_ws, size_t ws_size,
                              hipStream_t stream) {
    const float* X    = (const float*)d_in[0];
    const int*   arow = (const int*)d_in[1];
    const int*   acol = (const int*)d_in[2];
    const float* aval = (const float*)d_in[3];
    const float* W    = (const float*)d_in[4];
    const float* bias = (const float*)d_in[5];
    float*       out  = (float*)d_out;

    // ws: support bf16 25.6MB | Wt_sw 64KB | cursorA 6.3KB
    //     | epackA int2[NB*CAP] 16.4MB            total ~42.1MB
    char* ws = (char*)d_ws;
    unsigned short* support = (unsigned short*)ws;  ws += (size_t)N_NODES * OUT_F * 2;
    unsigned short* Wt = (unsigned short*)ws;       ws += (size_t)IN_F * OUT_F * 2;
    int*  cursorA = (int*)ws;                       ws += ((NB + 7) & ~7) * 4;
    int2* epackA  = (int2*)ws;

    wt_build<<<OUT_F, 256, 0, stream>>>(W, Wt, cursorA);
    fused_gp2<<<NFUSED, 256, 0, stream>>>(X, Wt, support,
                                          arow, acol, aval, cursorA, epackA);
    bucket_gather<<<NB, 256, 0, stream>>>(cursorA, epackA, support, bias, out);
}